// Round 4
// baseline (722.634 us; speedup 1.0000x reference)
//
#include <hip/hip_runtime.h>
#include <hip/hip_bf16.h>
#include <cstdint>
#include <cstddef>

#define B_ 4
#define S_ 2048
#define E_ 1024
#define H_ 16
#define D_ 64
#define NEG_BIG (-1e30f)

typedef __bf16 bf16x8 __attribute__((ext_vector_type(8)));
typedef float f32x4 __attribute__((ext_vector_type(4)));

__device__ __forceinline__ float bfu2f(unsigned short u) {
  unsigned v = ((unsigned)u) << 16;
  float f;
  __builtin_memcpy(&f, &v, 4);
  return f;
}
__device__ __forceinline__ unsigned short f2bfu(float f) {
  __hip_bfloat16 h = __float2bfloat16(f);   // RNE
  unsigned short u;
  __builtin_memcpy(&u, &h, 2);
  return u;
}

// ---------------- dtype probe ----------------
// If x is packed fp32, its even-index 16-bit halves are mantissa garbage
// (wild exponents ~80% of the time). If x is packed bf16, even-index
// elements are sane N(0,1) bf16s. flag: 0 = fp32 inputs, 1 = bf16 inputs.
__global__ __launch_bounds__(256) void probe_dtype(
    const unsigned short* __restrict__ xr, int* __restrict__ flagp) {
  __shared__ int cnt;
  if (threadIdx.x == 0) cnt = 0;
  __syncthreads();
  int bad = 0;
  for (int i = 0; i < 32; ++i) {
    unsigned short u = xr[(threadIdx.x * 32 + i) * 2];  // even index
    int e = (u >> 7) & 0xFF;
    if (e == 0xFF || e >= 0x90 || (e != 0 && e <= 0x60)) bad++;
  }
  atomicAdd(&cnt, bad);
  __syncthreads();
  if (threadIdx.x == 0) *flagp = (cnt > 512) ? 0 : 1;
}

// ---------------- converters (flag-dispatched) ----------------
__global__ __launch_bounds__(256) void convert_to_bf16(
    const void* __restrict__ in, unsigned short* __restrict__ out,
    const int* __restrict__ flagp, int off4, int n4) {
  int i = blockIdx.x * blockDim.x + threadIdx.x;
  if (i >= n4) return;
  ushort4 o;
  if (*flagp == 0) {
    float4 v = ((const float4*)in)[off4 + i];
    o.x = f2bfu(v.x); o.y = f2bfu(v.y); o.z = f2bfu(v.z); o.w = f2bfu(v.w);
  } else {
    o = ((const ushort4*)in)[off4 + i];
  }
  ((ushort4*)out)[i] = o;
}

__global__ __launch_bounds__(256) void convert_to_f32(
    const void* __restrict__ in, float* __restrict__ out,
    const int* __restrict__ flagp, int n) {
  int i = blockIdx.x * blockDim.x + threadIdx.x;
  if (i >= n) return;
  out[i] = (*flagp == 0) ? ((const float*)in)[i]
                         : bfu2f(((const unsigned short*)in)[i]);
}

// transpose + convert: out_bf16[C][R] = in[R][C]
__global__ __launch_bounds__(256) void transpose_conv(
    const void* __restrict__ in, unsigned short* __restrict__ out,
    const int* __restrict__ flagp, int R, int C) {
  __shared__ unsigned short t[32][33];
  const int flag = *flagp;
  const int c0 = blockIdx.x * 32, r0 = blockIdx.y * 32;
  const int lc = threadIdx.x & 31, lr = threadIdx.x >> 5;
  for (int i = 0; i < 4; ++i) {
    int r = lr + i * 8;
    size_t idx = (size_t)(r0 + r) * C + c0 + lc;
    t[r][lc] = (flag == 0) ? f2bfu(((const float*)in)[idx])
                           : ((const unsigned short*)in)[idx];
  }
  __syncthreads();
  for (int i = 0; i < 4; ++i) {
    int r = lr + i * 8;
    out[(size_t)(c0 + r) * R + r0 + lc] = t[lc][r];
  }
}

// final store: fp32 scratch -> d_out (fp32 or bf16 per flag)
__global__ __launch_bounds__(256) void store_out(
    const float* __restrict__ in, void* __restrict__ out,
    const int* __restrict__ flagp, int off4, int n4) {
  int i = blockIdx.x * blockDim.x + threadIdx.x;
  if (i >= n4) return;
  float4 v = ((const float4*)in)[i];
  if (*flagp == 0) {
    ((float4*)out)[off4 + i] = v;
  } else {
    ushort4 o;
    o.x = f2bfu(v.x); o.y = f2bfu(v.y); o.z = f2bfu(v.z); o.w = f2bfu(v.w);
    ((ushort4*)out)[off4 + i] = o;
  }
}

// ---------------- GEMM: C[M][N] = A[M][K] * Bt[N][K]^T + bias ----------------
// 128x128 tile, BK=32, 4 waves 2x2, wave 64x64 (4x4 MFMA). Register staging.
template <typename OutT>
__global__ __launch_bounds__(256) void gemm_bt_bias(
    const __hip_bfloat16* __restrict__ A,
    const __hip_bfloat16* __restrict__ Bt,
    const float* __restrict__ bias,
    OutT* __restrict__ C,
    int M, int N, int K) {
  __shared__ __align__(16) __hip_bfloat16 As[128 * 32];
  __shared__ __align__(16) __hip_bfloat16 Bs[128 * 32];
  const int tid = threadIdx.x;
  const int m0 = blockIdx.x * 128;
  const int n0 = blockIdx.y * 128;
  const int w = tid >> 6, lane = tid & 63;
  const int wm = (w & 1) * 64, wn = (w >> 1) * 64;
  const int lm = lane & 15, kg = lane >> 4;

  const int e0 = tid * 8, e1 = tid * 8 + 2048;
  const int ra = e0 >> 5, ca = e0 & 31;
  const int rb = e1 >> 5, cb = e1 & 31;

  f32x4 acc[4][4] = {};

  for (int k0 = 0; k0 < K; k0 += 32) {
    uint4 a0 = *(const uint4*)(A  + (size_t)(m0 + ra) * K + k0 + ca);
    uint4 a1 = *(const uint4*)(A  + (size_t)(m0 + rb) * K + k0 + cb);
    uint4 b0 = *(const uint4*)(Bt + (size_t)(n0 + ra) * K + k0 + ca);
    uint4 b1 = *(const uint4*)(Bt + (size_t)(n0 + rb) * K + k0 + cb);
    __syncthreads();
    *(uint4*)(As + e0) = a0;
    *(uint4*)(As + e1) = a1;
    *(uint4*)(Bs + e0) = b0;
    *(uint4*)(Bs + e1) = b1;
    __syncthreads();
    bf16x8 af[4], bfrag[4];
    for (int t = 0; t < 4; ++t)
      af[t] = *(const bf16x8*)(As + (wm + t * 16 + lm) * 32 + kg * 8);
    for (int t = 0; t < 4; ++t)
      bfrag[t] = *(const bf16x8*)(Bs + (wn + t * 16 + lm) * 32 + kg * 8);
    for (int tm = 0; tm < 4; ++tm)
      for (int tn = 0; tn < 4; ++tn)
        acc[tm][tn] = __builtin_amdgcn_mfma_f32_16x16x32_bf16(af[tm], bfrag[tn], acc[tm][tn], 0, 0, 0);
  }

  for (int tn = 0; tn < 4; ++tn) {
    int col = n0 + wn + tn * 16 + lm;
    float bv = bias[col];
    for (int tm = 0; tm < 4; ++tm) {
      int rbase = m0 + wm + tm * 16 + kg * 4;
      for (int r = 0; r < 4; ++r) {
        float v = acc[tm][tn][r] + bv;
        if constexpr (__is_same(OutT, float)) {
          C[(size_t)(rbase + r) * N + col] = v;
        } else {
          C[(size_t)(rbase + r) * N + col] = __float2bfloat16(v);
        }
      }
    }
  }
}

// ---------------- causal flash attention (one batch) ----------------
__global__ __launch_bounds__(256) void attn_causal(
    const __hip_bfloat16* __restrict__ qkv,  // [S][3E]
    const int* __restrict__ amask,           // [S]
    __hip_bfloat16* __restrict__ outp) {     // [S][E]
  __shared__ __align__(16) __hip_bfloat16 Qs[64 * 64];
  __shared__ __align__(16) __hip_bfloat16 Ks[64 * 64];
  __shared__ __align__(16) __hip_bfloat16 VT[64 * 64];
  __shared__ __align__(16) __hip_bfloat16 Ps[64 * 64];
  __shared__ float Ss[64 * 65];
  __shared__ float pmax[64 * 4], psum[64 * 4];
  __shared__ float mrun[64], lrun[64], alph[64];
  __shared__ int msk[64];

  const int tid = threadIdx.x;
  const int qt = blockIdx.x;
  const int h = blockIdx.y;
  const int q0 = qt * 64;
  const int w = tid >> 6, lane = tid & 63;
  const int lm = lane & 15, kg = lane >> 4;

  if (tid < 64) { mrun[tid] = NEG_BIG; lrun[tid] = 0.f; }

  {  // stage Q: Qs[q][d]
    const int e0 = tid * 8, e1 = tid * 8 + 2048;
    int r0 = e0 >> 6, c0 = e0 & 63, r1 = e1 >> 6, c1 = e1 & 63;
    uint4 v0 = *(const uint4*)(qkv + (size_t)(q0 + r0) * 3072 + h * 64 + c0);
    uint4 v1 = *(const uint4*)(qkv + (size_t)(q0 + r1) * 3072 + h * 64 + c1);
    *(uint4*)(Qs + e0) = v0;
    *(uint4*)(Qs + e1) = v1;
  }

  f32x4 oacc[4] = {};

  for (int j = 0; j <= qt; ++j) {
    const int j0 = j * 64;
    const int e0 = tid * 8, e1 = tid * 8 + 2048;
    const int r0 = e0 >> 6, c0 = e0 & 63, r1 = e1 >> 6, c1 = e1 & 63;
    uint4 kv0 = *(const uint4*)(qkv + (size_t)(j0 + r0) * 3072 + 1024 + h * 64 + c0);
    uint4 kv1 = *(const uint4*)(qkv + (size_t)(j0 + r1) * 3072 + 1024 + h * 64 + c1);
    const int key = lane, dg = w;
    const __hip_bfloat16* vsrc = qkv + (size_t)(j0 + key) * 3072 + 2048 + h * 64 + dg * 16;
    uint4 vv0 = *(const uint4*)(vsrc);
    uint4 vv1 = *(const uint4*)(vsrc + 8);
    int mval = (tid < 64) ? amask[j0 + tid] : 0;

    __syncthreads();
    *(uint4*)(Ks + e0) = kv0;
    *(uint4*)(Ks + e1) = kv1;
    {
      const __hip_bfloat16* p0 = (const __hip_bfloat16*)&vv0;
      const __hip_bfloat16* p1 = (const __hip_bfloat16*)&vv1;
      for (int e = 0; e < 8; ++e) VT[(dg * 16 + e) * 64 + key] = p0[e];
      for (int e = 0; e < 8; ++e) VT[(dg * 16 + 8 + e) * 64 + key] = p1[e];
    }
    if (tid < 64) msk[tid] = mval;
    __syncthreads();

    f32x4 sacc[4] = {};
    for (int ks = 0; ks < 2; ++ks) {
      bf16x8 aq = *(const bf16x8*)(Qs + (w * 16 + lm) * 64 + ks * 32 + kg * 8);
      for (int ct = 0; ct < 4; ++ct) {
        bf16x8 bk = *(const bf16x8*)(Ks + (ct * 16 + lm) * 64 + ks * 32 + kg * 8);
        sacc[ct] = __builtin_amdgcn_mfma_f32_16x16x32_bf16(aq, bk, sacc[ct], 0, 0, 0);
      }
    }
    for (int ct = 0; ct < 4; ++ct) {
      int kloc = ct * 16 + lm;
      int keyg = j0 + kloc;
      bool mk = msk[kloc] != 0;
      for (int r = 0; r < 4; ++r) {
        int rowq = w * 16 + kg * 4 + r;
        float s = (mk && keyg <= q0 + rowq) ? sacc[ct][r] * 0.125f : NEG_BIG;
        Ss[rowq * 65 + kloc] = s;
      }
    }
    __syncthreads();
    {
      int row = tid >> 2, seg = tid & 3;
      float mv = NEG_BIG;
      for (int c = 0; c < 16; ++c) mv = fmaxf(mv, Ss[row * 65 + seg * 16 + c]);
      pmax[row * 4 + seg] = mv;
    }
    __syncthreads();
    {
      int row = tid >> 2, seg = tid & 3;
      float mt = fmaxf(fmaxf(pmax[row * 4], pmax[row * 4 + 1]),
                       fmaxf(pmax[row * 4 + 2], pmax[row * 4 + 3]));
      float mn = fmaxf(mrun[row], mt);
      float sum = 0.f;
      for (int c = 0; c < 16; ++c) {
        float e = __expf(Ss[row * 65 + seg * 16 + c] - mn);
        Ps[row * 64 + seg * 16 + c] = __float2bfloat16(e);
        sum += e;
      }
      psum[row * 4 + seg] = sum;
    }
    __syncthreads();
    if (tid < 64) {
      int row = tid;
      float mt = fmaxf(fmaxf(pmax[row * 4], pmax[row * 4 + 1]),
                       fmaxf(pmax[row * 4 + 2], pmax[row * 4 + 3]));
      float mo = mrun[row];
      float mn = fmaxf(mo, mt);
      float a = __expf(mo - mn);
      float s4 = psum[row * 4] + psum[row * 4 + 1] + psum[row * 4 + 2] + psum[row * 4 + 3];
      lrun[row] = lrun[row] * a + s4;
      mrun[row] = mn;
      alph[row] = a;
    }
    __syncthreads();
    {
      float a0 = alph[w * 16 + kg * 4 + 0];
      float a1 = alph[w * 16 + kg * 4 + 1];
      float a2 = alph[w * 16 + kg * 4 + 2];
      float a3 = alph[w * 16 + kg * 4 + 3];
      for (int ct = 0; ct < 4; ++ct) {
        oacc[ct][0] *= a0; oacc[ct][1] *= a1;
        oacc[ct][2] *= a2; oacc[ct][3] *= a3;
      }
      for (int ks = 0; ks < 2; ++ks) {
        bf16x8 ap = *(const bf16x8*)(Ps + (w * 16 + lm) * 64 + ks * 32 + kg * 8);
        for (int ct = 0; ct < 4; ++ct) {
          bf16x8 bv = *(const bf16x8*)(VT + (ct * 16 + lm) * 64 + ks * 32 + kg * 8);
          oacc[ct] = __builtin_amdgcn_mfma_f32_16x16x32_bf16(ap, bv, oacc[ct], 0, 0, 0);
        }
      }
    }
  }

  {
    float linv[4];
    for (int r = 0; r < 4; ++r) {
      float l = lrun[w * 16 + kg * 4 + r];
      linv[r] = (l > 0.f) ? 1.f / l : 0.f;
    }
    for (int ct = 0; ct < 4; ++ct) {
      int col = h * 64 + ct * 16 + lm;
      for (int r = 0; r < 4; ++r) {
        int rowq = w * 16 + kg * 4 + r;
        outp[(size_t)(q0 + rowq) * 1024 + col] = __float2bfloat16(oacc[ct][r] * linv[r]);
      }
    }
  }
}

extern "C" void kernel_launch(void* const* d_in, const int* in_sizes, int n_in,
                              void* d_out, int out_size, void* d_ws, size_t ws_size,
                              hipStream_t stream) {
  const void* x      = d_in[0];
  const int*  amask  = (const int*)d_in[1];
  const void* W_qkv  = d_in[2];
  const void* b_qkv  = d_in[3];
  const void* W_proj = d_in[4];
  const void* b_proj = d_in[5];

  // Workspace layout (bytes), total 40MB:
  //   [0]        flag (int)
  //   [1K]       bq   fp32 [3072]
  //   [16K]      bp   fp32 [1024]
  //   [32K]      WqkvT  bf16 [3072][1024]  (6MB)
  //   [8M]       WprojT bf16 [1024][1024]  (2MB)
  //   [12M]      xb_b   bf16 [2048][1024]  (4MB)
  //   [16M]      qkv_b  bf16 [2048][3072]  (12MB)
  //   [28M]      attno_b bf16 [2048][1024] (4MB)
  //   [32M]      outf_b fp32 [2048][1024]  (8MB)
  char* ws = (char*)d_ws;
  int*            flag    = (int*)ws;
  float*          bq      = (float*)(ws + 1024);
  float*          bp      = (float*)(ws + 16384);
  unsigned short* WqkvT_u = (unsigned short*)(ws + 32768);
  unsigned short* WprojT_u= (unsigned short*)(ws + (8u << 20));
  unsigned short* xb_u    = (unsigned short*)(ws + (12u << 20));
  unsigned short* qkv_u   = (unsigned short*)(ws + (16u << 20));
  unsigned short* attno_u = (unsigned short*)(ws + (28u << 20));
  float*          outf    = (float*)(ws + (32u << 20));

  const __hip_bfloat16* WqkvT = (const __hip_bfloat16*)WqkvT_u;
  const __hip_bfloat16* WprojT = (const __hip_bfloat16*)WprojT_u;
  __hip_bfloat16* xb    = (__hip_bfloat16*)xb_u;
  __hip_bfloat16* qkv_b = (__hip_bfloat16*)qkv_u;
  __hip_bfloat16* attno = (__hip_bfloat16*)attno_u;

  probe_dtype<<<1, 256, 0, stream>>>((const unsigned short*)x, flag);
  convert_to_f32<<<12, 256, 0, stream>>>(b_qkv, bq, flag, 3072);
  convert_to_f32<<<4, 256, 0, stream>>>(b_proj, bp, flag, 1024);
  transpose_conv<<<dim3(3072 / 32, 1024 / 32), 256, 0, stream>>>(W_qkv, WqkvT_u, flag, 1024, 3072);
  transpose_conv<<<dim3(1024 / 32, 1024 / 32), 256, 0, stream>>>(W_proj, WprojT_u, flag, 1024, 1024);

  const int n4 = (S_ * E_) / 4;  // 524288 quads per batch
  for (int b = 0; b < B_; ++b) {
    const int off4 = b * n4;
    convert_to_bf16<<<n4 / 256, 256, 0, stream>>>(x, xb_u, flag, off4, n4);
    gemm_bt_bias<__hip_bfloat16><<<dim3(S_ / 128, 3072 / 128), 256, 0, stream>>>(
        xb, WqkvT, bq, qkv_b, S_, 3072, 1024);
    attn_causal<<<dim3(S_ / 64, H_), 256, 0, stream>>>(qkv_b, amask + (size_t)b * S_, attno);
    gemm_bt_bias<float><<<dim3(S_ / 128, 1024 / 128), 256, 0, stream>>>(
        attno, WprojT, bp, outf, S_, 1024, 1024);
    store_out<<<n4 / 256, 256, 0, stream>>>(outf, d_out, flag, off4, n4);
  }
}

// Round 5
// 422.938 us; speedup vs baseline: 1.7086x; 1.7086x over previous
//
#include <hip/hip_runtime.h>
#include <hip/hip_bf16.h>
#include <cstdint>
#include <cstddef>

#define B_ 4
#define S_ 2048
#define E_ 1024
#define H_ 16
#define D_ 64
#define NEG_BIG (-1e30f)

typedef __bf16 bf16x8 __attribute__((ext_vector_type(8)));
typedef __bf16 bf16x4v __attribute__((ext_vector_type(4)));
typedef float f32x4 __attribute__((ext_vector_type(4)));

__device__ __forceinline__ void async_copy16(void* lds, const void* g) {
  __builtin_amdgcn_global_load_lds(
      (const __attribute__((address_space(1))) void*)g,
      (__attribute__((address_space(3))) void*)lds, 16, 0, 0);
}

__device__ __forceinline__ float bfu2f(unsigned short u) {
  unsigned v = ((unsigned)u) << 16;
  float f;
  __builtin_memcpy(&f, &v, 4);
  return f;
}
__device__ __forceinline__ unsigned short f2bfu(float f) {
  __hip_bfloat16 h = __float2bfloat16(f);  // RNE
  unsigned short u;
  __builtin_memcpy(&u, &h, 2);
  return u;
}
__device__ __forceinline__ unsigned pk2(float a, float b) {
  return (unsigned)f2bfu(a) | ((unsigned)f2bfu(b) << 16);
}

// ---------------- dtype probe (proven round 4) ----------------
__global__ __launch_bounds__(256) void probe_dtype(
    const unsigned short* __restrict__ xr, int* __restrict__ flagp) {
  __shared__ int cnt;
  if (threadIdx.x == 0) cnt = 0;
  __syncthreads();
  int bad = 0;
  for (int i = 0; i < 32; ++i) {
    unsigned short u = xr[(threadIdx.x * 32 + i) * 2];
    int e = (u >> 7) & 0xFF;
    if (e == 0xFF || e >= 0x90 || (e != 0 && e <= 0x60)) bad++;
  }
  atomicAdd(&cnt, bad);
  __syncthreads();
  if (threadIdx.x == 0) *flagp = (cnt > 512) ? 0 : 1;  // 0=fp32, 1=bf16
}

__global__ __launch_bounds__(256) void convert_to_f32(
    const void* __restrict__ in, float* __restrict__ out,
    const int* __restrict__ flagp, int n) {
  int i = blockIdx.x * blockDim.x + threadIdx.x;
  if (i >= n) return;
  out[i] = (*flagp == 0) ? ((const float*)in)[i]
                         : bfu2f(((const unsigned short*)in)[i]);
}

// transpose + convert: out_bf16[C][R] = in[R][C]   (proven round 4)
__global__ __launch_bounds__(256) void transpose_conv(
    const void* __restrict__ in, unsigned short* __restrict__ out,
    const int* __restrict__ flagp, int R, int C) {
  __shared__ unsigned short t[32][33];
  const int flag = *flagp;
  const int c0 = blockIdx.x * 32, r0 = blockIdx.y * 32;
  const int lc = threadIdx.x & 31, lr = threadIdx.x >> 5;
  for (int i = 0; i < 4; ++i) {
    int r = lr + i * 8;
    size_t idx = (size_t)(r0 + r) * C + c0 + lc;
    t[r][lc] = (flag == 0) ? f2bfu(((const float*)in)[idx])
                           : ((const unsigned short*)in)[idx];
  }
  __syncthreads();
  for (int i = 0; i < 4; ++i) {
    int r = lr + i * 8;
    out[(size_t)(c0 + r) * R + r0 + lc] = t[lc][r];
  }
}

// -------- GEMM1: qkv = x(fp32|bf16) @ WqkvT^T + bias, out bf16 --------
// 128x128 tile BK=32; A: register-staged + inline convert; B: global_load_lds.
__global__ __launch_bounds__(256) void gemm_x_w(
    const void* __restrict__ Xin, long long xoff,
    const __hip_bfloat16* __restrict__ Bt,
    const float* __restrict__ bias,
    const int* __restrict__ flagp,
    __hip_bfloat16* __restrict__ C,
    int M, int N, int K) {
  __shared__ __align__(16) __hip_bfloat16 As[128 * 32];
  __shared__ __align__(16) __hip_bfloat16 Bs[128 * 32];
  const int flag = *flagp;
  const int tid = threadIdx.x;
  const int m0 = blockIdx.x * 128, n0 = blockIdx.y * 128;
  const int w = tid >> 6, lane = tid & 63;
  const int wm = (w & 1) * 64, wn = (w >> 1) * 64;
  const int lm = lane & 15, kg = lane >> 4;
  const int e0 = tid * 8, e1 = tid * 8 + 2048;
  const int ra = e0 >> 5, ca = e0 & 31, rb = e1 >> 5, cb = e1 & 31;

  f32x4 acc[4][4] = {};

  for (int k0 = 0; k0 < K; k0 += 32) {
    uint4 aw0, aw1;
    if (flag == 0) {
      const float* A32 = (const float*)Xin + xoff;
      float4 f0 = *(const float4*)(A32 + (size_t)(m0 + ra) * K + k0 + ca);
      float4 f1 = *(const float4*)(A32 + (size_t)(m0 + ra) * K + k0 + ca + 4);
      float4 f2 = *(const float4*)(A32 + (size_t)(m0 + rb) * K + k0 + cb);
      float4 f3 = *(const float4*)(A32 + (size_t)(m0 + rb) * K + k0 + cb + 4);
      aw0 = make_uint4(pk2(f0.x, f0.y), pk2(f0.z, f0.w), pk2(f1.x, f1.y), pk2(f1.z, f1.w));
      aw1 = make_uint4(pk2(f2.x, f2.y), pk2(f2.z, f2.w), pk2(f3.x, f3.y), pk2(f3.z, f3.w));
    } else {
      const unsigned short* A16 = (const unsigned short*)Xin + xoff;
      aw0 = *(const uint4*)(A16 + (size_t)(m0 + ra) * K + k0 + ca);
      aw1 = *(const uint4*)(A16 + (size_t)(m0 + rb) * K + k0 + cb);
    }
    __syncthreads();                 // prior-iter LDS reads done
    *(uint4*)(As + e0) = aw0;
    *(uint4*)(As + e1) = aw1;
    for (int c = 0; c < 2; ++c) {    // B via async DMA
      int o = tid * 16 + c * 4096;
      int e = o >> 1, row = e >> 5, col = e & 31;
      async_copy16((char*)Bs + o, (const char*)(Bt + (size_t)(n0 + row) * K + k0 + col));
    }
    __syncthreads();                 // drains lgkm (As) + vmcnt (Bs DMA)
    bf16x8 af[4], bfrag[4];
    for (int t = 0; t < 4; ++t)
      af[t] = *(const bf16x8*)(As + (wm + t * 16 + lm) * 32 + kg * 8);
    for (int t = 0; t < 4; ++t)
      bfrag[t] = *(const bf16x8*)(Bs + (wn + t * 16 + lm) * 32 + kg * 8);
    for (int tm = 0; tm < 4; ++tm)
      for (int tn = 0; tn < 4; ++tn)
        acc[tm][tn] = __builtin_amdgcn_mfma_f32_16x16x32_bf16(af[tm], bfrag[tn], acc[tm][tn], 0, 0, 0);
  }

  for (int tn = 0; tn < 4; ++tn) {
    int col = n0 + wn + tn * 16 + lm;
    float bv = bias[col];
    for (int tm = 0; tm < 4; ++tm) {
      int rbase = m0 + wm + tm * 16 + kg * 4;
      for (int r = 0; r < 4; ++r)
        C[(size_t)(rbase + r) * N + col] = __float2bfloat16(acc[tm][tn][r] + bv);
    }
  }
}

// -------- GEMM2: out = attno @ WprojT^T + bias; out dtype by flag --------
__global__ __launch_bounds__(256) void gemm_p_out(
    const __hip_bfloat16* __restrict__ A,
    const __hip_bfloat16* __restrict__ Bt,
    const float* __restrict__ bias,
    const int* __restrict__ flagp,
    void* __restrict__ Cv, long long coff,
    int M, int N, int K) {
  __shared__ __align__(16) __hip_bfloat16 As[128 * 32];
  __shared__ __align__(16) __hip_bfloat16 Bs[128 * 32];
  const int flag = *flagp;
  const int tid = threadIdx.x;
  const int m0 = blockIdx.x * 128, n0 = blockIdx.y * 128;
  const int w = tid >> 6, lane = tid & 63;
  const int wm = (w & 1) * 64, wn = (w >> 1) * 64;
  const int lm = lane & 15, kg = lane >> 4;

  f32x4 acc[4][4] = {};

  for (int k0 = 0; k0 < K; k0 += 32) {
    __syncthreads();
    for (int c = 0; c < 2; ++c) {
      int o = tid * 16 + c * 4096;
      int e = o >> 1, row = e >> 5, col = e & 31;
      async_copy16((char*)As + o, (const char*)(A + (size_t)(m0 + row) * K + k0 + col));
      async_copy16((char*)Bs + o, (const char*)(Bt + (size_t)(n0 + row) * K + k0 + col));
    }
    __syncthreads();
    bf16x8 af[4], bfrag[4];
    for (int t = 0; t < 4; ++t)
      af[t] = *(const bf16x8*)(As + (wm + t * 16 + lm) * 32 + kg * 8);
    for (int t = 0; t < 4; ++t)
      bfrag[t] = *(const bf16x8*)(Bs + (wn + t * 16 + lm) * 32 + kg * 8);
    for (int tm = 0; tm < 4; ++tm)
      for (int tn = 0; tn < 4; ++tn)
        acc[tm][tn] = __builtin_amdgcn_mfma_f32_16x16x32_bf16(af[tm], bfrag[tn], acc[tm][tn], 0, 0, 0);
  }

  for (int tn = 0; tn < 4; ++tn) {
    int col = n0 + wn + tn * 16 + lm;
    float bv = bias[col];
    for (int tm = 0; tm < 4; ++tm) {
      int rbase = m0 + wm + tm * 16 + kg * 4;
      for (int r = 0; r < 4; ++r) {
        float v = acc[tm][tn][r] + bv;
        size_t idx = (size_t)coff + (size_t)(rbase + r) * N + col;
        if (flag == 0) ((float*)Cv)[idx] = v;
        else           ((unsigned short*)Cv)[idx] = f2bfu(v);
      }
    }
  }
}

// -------- causal flash attention, S^T formulation, in-register softmax ----
// grid: (S/64, bsz*H). Each block: one 64-q tile of one (b,h).
// Per wave: 16 q-columns (q = q0 + w*16 + lm). 2 barriers per K-tile.
__global__ __launch_bounds__(256) void attn_flash(
    const __hip_bfloat16* __restrict__ qkv,  // [bsz*S][3072]
    const int* __restrict__ amask,           // [bsz*S]
    __hip_bfloat16* __restrict__ outp) {     // [bsz*S][1024]
  __shared__ __align__(16) __hip_bfloat16 Ks[64 * 64];   // [key][d]
  __shared__ __align__(16) __hip_bfloat16 VT[64 * 80];   // [d][key], pad 80
  __shared__ __align__(16) __hip_bfloat16 Ps[4 * 16 * 80]; // wave-private P

  const int tid = threadIdx.x;
  const int qt = blockIdx.x, bh = blockIdx.y;
  const int b = bh >> 4, h = bh & 15;
  const int q0 = qt * 64;
  const size_t rowbase = (size_t)b * S_;
  const int w = tid >> 6, lane = tid & 63;
  const int lm = lane & 15, kg = lane >> 4;
  const int qg = q0 + w * 16 + lm;           // this lane's q (S^T column)
  __hip_bfloat16* PsW = Ps + w * (16 * 80);

  // Q fragments in registers (B-operand of S^T = K·Q^T), loaded once
  bf16x8 bq0 = *(const bf16x8*)(qkv + (rowbase + qg) * 3072 + h * 64 + kg * 8);
  bf16x8 bq1 = *(const bf16x8*)(qkv + (rowbase + qg) * 3072 + h * 64 + 32 + kg * 8);

  float mrow = NEG_BIG, lrow = 0.f;
  f32x4 oacc[4] = {};   // O[m=q][n=d]: row q=kg*4+r (+w*16), col d=ct2*16+lm

  for (int j = 0; j <= qt; ++j) {
    const int j0 = j * 64;
    // prefetch V + pad-mask into registers (before barrier)
    const __hip_bfloat16* vsrc = qkv + (rowbase + j0 + lane) * 3072 + 2048 + h * 64 + w * 16;
    uint4 vv0 = *(const uint4*)vsrc;
    uint4 vv1 = *(const uint4*)(vsrc + 8);
    int4 mk[4];
    #pragma unroll
    for (int ct = 0; ct < 4; ++ct)
      mk[ct] = *(const int4*)(amask + rowbase + j0 + ct * 16 + kg * 4);

    __syncthreads();  // A: prior-iter Ks/VT reads complete
    {  // K tile via async DMA
      const char* kb = (const char*)(qkv + (rowbase + j0) * 3072 + 1024 + h * 64);
      for (int c = 0; c < 2; ++c) {
        int o = tid * 16 + c * 4096;
        async_copy16((char*)Ks + o, kb + (size_t)(o >> 7) * 6144 + (o & 127));
      }
    }
    {  // V transposed -> VT[d][key], stride 80 (2-way conflicts = free)
      const __hip_bfloat16* p0 = (const __hip_bfloat16*)&vv0;
      const __hip_bfloat16* p1 = (const __hip_bfloat16*)&vv1;
      #pragma unroll
      for (int e = 0; e < 8; ++e) VT[(w * 16 + e) * 80 + lane] = p0[e];
      #pragma unroll
      for (int e = 0; e < 8; ++e) VT[(w * 16 + 8 + e) * 80 + lane] = p1[e];
    }
    __syncthreads();  // B: drains vmcnt (K DMA) + lgkm (VT writes)

    // S^T = K · Q^T  (A=Ks[key][d], B=Q[q][d]); D: row=key, col=q
    f32x4 sacc[4] = {};
    #pragma unroll
    for (int ks = 0; ks < 2; ++ks) {
      bf16x8 bq = ks ? bq1 : bq0;
      #pragma unroll
      for (int ct = 0; ct < 4; ++ct) {
        bf16x8 ak = *(const bf16x8*)(Ks + (ct * 16 + lm) * 64 + ks * 32 + kg * 8);
        sacc[ct] = __builtin_amdgcn_mfma_f32_16x16x32_bf16(ak, bq, sacc[ct], 0, 0, 0);
      }
    }
    // scale + causal + pad mask; per-lane then cross-kg reduction
    float sc[4][4];
    float mt = NEG_BIG;
    #pragma unroll
    for (int ct = 0; ct < 4; ++ct) {
      const int* mp = (const int*)&mk[ct];
      #pragma unroll
      for (int r = 0; r < 4; ++r) {
        int keyg = j0 + ct * 16 + kg * 4 + r;
        float s = (mp[r] != 0 && keyg <= qg) ? sacc[ct][r] * 0.125f : NEG_BIG;
        sc[ct][r] = s;
        mt = fmaxf(mt, s);
      }
    }
    mt = fmaxf(mt, __shfl_xor(mt, 16));
    mt = fmaxf(mt, __shfl_xor(mt, 32));
    float mn = fmaxf(mrow, mt);
    float a = __expf(mrow - mn);   // first iter: ~0
    float ps = 0.f;
    #pragma unroll
    for (int ct = 0; ct < 4; ++ct) {
      float p0 = __expf(sc[ct][0] - mn), p1 = __expf(sc[ct][1] - mn);
      float p2 = __expf(sc[ct][2] - mn), p3 = __expf(sc[ct][3] - mn);
      ps += (p0 + p1) + (p2 + p3);
      bf16x4v pv;
      pv[0] = (__bf16)p0; pv[1] = (__bf16)p1; pv[2] = (__bf16)p2; pv[3] = (__bf16)p3;
      *(bf16x4v*)(PsW + lm * 80 + ct * 16 + kg * 4) = pv;   // wave-private
    }
    ps += __shfl_xor(ps, 16);
    ps += __shfl_xor(ps, 32);
    lrow = lrow * a + ps;
    mrow = mn;
    // alpha lives at lane lm=q; oacc rows are q=kg*4+r -> broadcast
    float al[4];
    #pragma unroll
    for (int r = 0; r < 4; ++r) al[r] = __shfl(a, kg * 4 + r);
    #pragma unroll
    for (int ct2 = 0; ct2 < 4; ++ct2) {
      oacc[ct2][0] *= al[0]; oacc[ct2][1] *= al[1];
      oacc[ct2][2] *= al[2]; oacc[ct2][3] *= al[3];
    }
    // O += P·V  (A=P[q][key] from wave-private LDS; B=VT[d][key]).
    // Same-wave ds_write -> ds_read: DS pipe is in-order per wave; no barrier.
    #pragma unroll
    for (int ks = 0; ks < 2; ++ks) {
      bf16x8 ap = *(const bf16x8*)(PsW + lm * 80 + ks * 32 + kg * 8);
      #pragma unroll
      for (int ct2 = 0; ct2 < 4; ++ct2) {
        bf16x8 bv = *(const bf16x8*)(VT + (ct2 * 16 + lm) * 80 + ks * 32 + kg * 8);
        oacc[ct2] = __builtin_amdgcn_mfma_f32_16x16x32_bf16(ap, bv, oacc[ct2], 0, 0, 0);
      }
    }
  }

  {  // epilogue: O / l
    float linv = (lrow > 0.f) ? 1.f / lrow : 0.f;
    float li[4];
    #pragma unroll
    for (int r = 0; r < 4; ++r) li[r] = __shfl(linv, kg * 4 + r);
    #pragma unroll
    for (int ct2 = 0; ct2 < 4; ++ct2) {
      #pragma unroll
      for (int r = 0; r < 4; ++r) {
        int rowq = q0 + w * 16 + kg * 4 + r;
        outp[(rowbase + rowq) * 1024 + h * 64 + ct2 * 16 + lm] =
            __float2bfloat16(oacc[ct2][r] * li[r]);
      }
    }
  }
}

extern "C" void kernel_launch(void* const* d_in, const int* in_sizes, int n_in,
                              void* d_out, int out_size, void* d_ws, size_t ws_size,
                              hipStream_t stream) {
  // ws layout: [0] flag | [1K] bq fp32 | [16K] bp fp32 | [32K] WqkvT 6MB |
  // [32K+6MB] WprojT 2MB | [32K+8MB] big: qkv (+ attno).
  // merged (ws>=80MB): qkv 48MB + attno 16MB, single-pass over all batches.
  // fallback: qkv_b 12MB + attno_b 4MB, per-batch loop (proven at 40MB ws).
  const bool merged = (ws_size >= (80ull << 20));
  char* ws = (char*)d_ws;
  int*            flag   = (int*)ws;
  float*          bq     = (float*)(ws + 1024);
  float*          bp     = (float*)(ws + 16384);
  unsigned short* WqkvTu = (unsigned short*)(ws + 32768);
  unsigned short* WprojTu= (unsigned short*)(ws + 32768 + 6291456);
  char*           big    = ws + 32768 + 8388608;
  __hip_bfloat16* qkv    = (__hip_bfloat16*)big;
  __hip_bfloat16* attno  = (__hip_bfloat16*)(big + (merged ? 50331648u : 12582912u));

  probe_dtype<<<1, 256, 0, stream>>>((const unsigned short*)d_in[0], flag);
  convert_to_f32<<<12, 256, 0, stream>>>(d_in[3], bq, flag, 3072);
  convert_to_f32<<<4, 256, 0, stream>>>(d_in[5], bp, flag, 1024);
  transpose_conv<<<dim3(96, 32), 256, 0, stream>>>(d_in[2], WqkvTu, flag, 1024, 3072);
  transpose_conv<<<dim3(32, 32), 256, 0, stream>>>(d_in[4], WprojTu, flag, 1024, 1024);

  const int nchunk = merged ? 1 : B_;
  const int bsz = merged ? B_ : 1;
  const int Mc = bsz * S_;
  for (int c = 0; c < nchunk; ++c) {
    long long off = (long long)c * S_ * E_;  // element offset (bsz=1 in loop mode)
    gemm_x_w<<<dim3(Mc / 128, 3072 / 128), 256, 0, stream>>>(
        d_in[0], off, (const __hip_bfloat16*)WqkvTu, bq, flag, qkv, Mc, 3072, 1024);
    attn_flash<<<dim3(S_ / 64, bsz * H_), 256, 0, stream>>>(
        qkv, (const int*)d_in[1] + (size_t)c * S_, attno);
    gemm_p_out<<<dim3(Mc / 128, 1024 / 128), 256, 0, stream>>>(
        attno, (const __hip_bfloat16*)WprojTu, bp, flag, d_out, off, Mc, 1024, 1024);
  }
}